// Round 1
// baseline (165.819 us; speedup 1.0000x reference)
//
#include <hip/hip_runtime.h>
#include <cstdint>

#define DIMD 1024
#define NROWS 8192
#define KDIM 2048   // 2*DIM

typedef unsigned short u16;
typedef __bf16 bf16x8 __attribute__((ext_vector_type(8)));
typedef float f32x4 __attribute__((ext_vector_type(4)));

__device__ __forceinline__ u16 f2bf(float f) {
  unsigned u = __builtin_bit_cast(unsigned, f);
  return (u16)((u + 0x7FFFu + ((u >> 16) & 1u)) >> 16);  // RNE
}

// Branch-free exact-enough GELU (A&S 7.1.26 erf, |err| <= 1.5e-7).
__device__ __forceinline__ float gelu_exact(float x) {
  float s = 0.70710678118654752f * x;
  float a = fabsf(s);
  float k = __fdividef(1.0f, fmaf(0.3275911f, a, 1.0f));
  float p = 1.061405429f;
  p = fmaf(p, k, -1.453152027f);
  p = fmaf(p, k, 1.421413741f);
  p = fmaf(p, k, -0.284496736f);
  p = fmaf(p, k, 0.254829592f);
  p = p * k;
  float e = __expf(-s * s);
  float erf_s = copysignf(fmaf(-p, e, 1.0f), s);
  return 0.5f * x * (1.0f + erf_s);
}

// ---------------------------------------------------------------------------
// Fused pre-kernel: conv(3x5)+bias+gelu -> x2 bf16, and w2 fp32->bf16 cast.
// (unchanged from previous round)
// ---------------------------------------------------------------------------
__global__ __launch_bounds__(256) void pre_kernel(
    const float* __restrict__ ifeats, const float* __restrict__ tn,
    const float* __restrict__ ta, const float* __restrict__ cw,
    const float* __restrict__ cb, const float* __restrict__ w2,
    u16* __restrict__ x2, u16* __restrict__ w2b) {
  const int b = blockIdx.x;
  const int t = threadIdx.x;
  if (b < NROWS) {
    __shared__ float si[DIMD], sn[DIMD], sa[DIMD];
    ((float4*)si)[t] = ((const float4*)(ifeats + (size_t)b * DIMD))[t];
    ((float4*)sn)[t] = ((const float4*)tn)[t];
    ((float4*)sa)[t] = ((const float4*)ta)[t];
    __syncthreads();
    const int c = t >> 7;
    const int w0 = (t & 127) << 3;
    float cwn[5], cwa[5], cwi[5];
#pragma unroll
    for (int k = 0; k < 5; ++k) {
      cwn[k] = cw[c * 15 + k];
      cwa[k] = cw[c * 15 + 5 + k];
      cwi[k] = cw[c * 15 + 10 + k];
    }
    const float bias = cb[c];
    float wn[12], wa[12], wi[12];
#pragma unroll
    for (int j = 0; j < 12; ++j) {
      int wp = w0 - 2 + j;
      bool ok = (wp >= 0) && (wp < DIMD);
      wn[j] = ok ? sn[wp] : 0.f;
      wa[j] = ok ? sa[wp] : 0.f;
      wi[j] = ok ? si[wp] : 0.f;
    }
    union { u16 o[8]; uint4 u; } pk;
#pragma unroll
    for (int s = 0; s < 8; ++s) {
      float x = bias;
#pragma unroll
      for (int k = 0; k < 5; ++k) {
        x = fmaf(cwn[k], wn[s + k], x);
        x = fmaf(cwa[k], wa[s + k], x);
        x = fmaf(cwi[k], wi[s + k], x);
      }
      pk.o[s] = f2bf(gelu_exact(x));
    }
    *(uint4*)(x2 + (size_t)b * KDIM + c * DIMD + w0) = pk.u;
  } else {
    const int t2 = (b - NROWS) * 256 + t;
    const float4* p = (const float4*)(w2 + (size_t)t2 * 8);
    float4 a = p[0], bb = p[1];
    union { u16 o[8]; uint4 v; } pk;
    pk.o[0] = f2bf(a.x);  pk.o[1] = f2bf(a.y);  pk.o[2] = f2bf(a.z);  pk.o[3] = f2bf(a.w);
    pk.o[4] = f2bf(bb.x); pk.o[5] = f2bf(bb.y); pk.o[6] = f2bf(bb.z); pk.o[7] = f2bf(bb.w);
    *(uint4*)(w2b + (size_t)t2 * 8) = pk.v;
  }
}

// ---------------------------------------------------------------------------
// GEMM v3: counted-vmcnt phase pipeline (T3+T4+T5).
//   128x128 tile, 4 waves (256 thr), per-wave 64x64 (4x4 acc -> 32.8 FLOP/B,
//   1.5x less LDS frag traffic than 64x32). BK=32, 3-deep LDS rotation
//   (48 KB static -> 2 blocks/CU). Per K-tile: 2 phases, each
//   {ds_read frags | issue tile t+2 loads -> s_barrier -> setprio+8 MFMA ->
//    s_barrier}; ONE vmcnt(4) per K-tile (never 0 in steady state): tile t+2
//   issued iter t into the buffer freed at iter t-1, drained end of iter t+1
//   (~2 iters ≈ 2200 cyc slack > 900 cyc HBM latency).
// Swizzle (BK=32 => 4 x 16B chunks/row): LDS[row][c] holds global chunk
//   c ^ ((row>>1)&3); read addr chunk = quad ^ ((r16>>1)&3) -> max 2-way
//   bank aliasing (free per m136). global_load_lds dest stays linear,
//   source is pre-swizzled (m173 pattern).
// ---------------------------------------------------------------------------
__device__ __forceinline__ void gl_lds16(const u16* g, u16* l) {
  __builtin_amdgcn_global_load_lds(
      (__attribute__((address_space(1))) void*)g,
      (__attribute__((address_space(3))) void*)l, 16, 0, 0);
}

#define BK 32       // u16 per row per K-tile
#define NTILE 64    // KDIM / BK

__global__ __launch_bounds__(256, 2) void gemm_bt(
    const u16* __restrict__ A,      // x2 bf16 [8192, 2048]
    const u16* __restrict__ B,      // w2 bf16 [1024, 2048]
    const float* __restrict__ ifeats,
    const float* __restrict__ b2,
    float* __restrict__ out) {
  __shared__ __align__(16) u16 sA[3][128 * BK];  // 3 x 8 KB
  __shared__ __align__(16) u16 sB[3][128 * BK];  // 3 x 8 KB; 48 KB total

  const int tid = threadIdx.x;
  const int wv = tid >> 6;         // wave 0..3
  const int lane = tid & 63;
  // XCD-aware swizzle (unchanged): xcd owns i-strips -> A-panel L2 reuse.
  const int id = blockIdx.x;       // 0..511
  const int xcd = id & 7;
  const int s_ = id >> 3;          // 0..63
  const int i0 = (xcd * 8 + (s_ >> 3)) * 128;
  const int j0 = (s_ & 7) * 128;

  const int wm = (wv & 1) * 64;    // wave tile: 64 (M) x 64 (N)
  const int wn = (wv >> 1) * 64;
  const int quad = lane >> 4;      // K-chunk selector (0..3)
  const int r16 = lane & 15;
  const int csw = (r16 >> 1) & 3;  // read-side chunk swizzle

  // Staging: unit = 64 rows x 64 B = one gl_lds16 per thread (256 thr x 16B).
  // A tile = 2 units, B tile = 2 units. Per-thread global source, chunk
  // pre-swizzled to match read-side: chunk = (tid&3) ^ ((row>>1)&3).
  const int grow = tid >> 2;                         // 0..63
  const int gchk = (tid & 3) ^ ((tid >> 3) & 3);     // == (tid&3)^((grow>>1)&3)
  const u16* gA[2];
  const u16* gB[2];
#pragma unroll
  for (int u = 0; u < 2; ++u) {
    gA[u] = A + (size_t)(i0 + u * 64 + grow) * KDIM + gchk * 8;
    gB[u] = B + (size_t)(j0 + u * 64 + grow) * KDIM + gchk * 8;
  }
  const int ldsoff = wv * 16 * BK;  // wave's 16-row slice inside a 64-row unit

  const f32x4 vzero = {0.f, 0.f, 0.f, 0.f};
  f32x4 acc[4][4];
#pragma unroll
  for (int a = 0; a < 4; ++a)
#pragma unroll
    for (int b = 0; b < 4; ++b) acc[a][b] = vzero;

  u16* a0 = (u16*)sA[0]; u16* a1 = (u16*)sA[1]; u16* a2 = (u16*)sA[2];
  u16* b0 = (u16*)sB[0]; u16* b1 = (u16*)sB[1]; u16* b2s = (u16*)sB[2];

  auto issueA = [&](u16* buf, int t, int u) {
    gl_lds16(gA[u] + t * BK, buf + u * 64 * BK + ldsoff);
  };
  auto issueB = [&](u16* buf, int t, int u) {
    gl_lds16(gB[u] + t * BK, buf + u * 64 * BK + ldsoff);
  };
  auto ldfrag = [&](const u16* buf, int row) -> bf16x8 {
    return *(const bf16x8*)&buf[(row + r16) * BK + ((quad ^ csw) << 3)];
  };

  // Prologue: tile0 -> buf0, tile1 -> buf1 (4 loads each). Drain tile0 only.
  issueA(a0, 0, 0); issueA(a0, 0, 1); issueB(b0, 0, 0); issueB(b0, 0, 1);
  issueA(a1, 1, 0); issueA(a1, 1, 1); issueB(b1, 1, 0); issueB(b1, 1, 1);
  asm volatile("s_waitcnt vmcnt(4)" ::: "memory");
  __builtin_amdgcn_s_barrier();

  for (int t = 0; t < NTILE; ++t) {
    const bool pf = (t + 2) < NTILE;
    // ---------------- phase 1: top half of C (acc[0..1][*]) ----------------
    bf16x8 av0 = ldfrag(a0, wm);
    bf16x8 av1 = ldfrag(a0, wm + 16);
    bf16x8 bv0 = ldfrag(b0, wn);
    bf16x8 bv1 = ldfrag(b0, wn + 16);
    bf16x8 bv2 = ldfrag(b0, wn + 32);
    bf16x8 bv3 = ldfrag(b0, wn + 48);
    if (pf) { issueA(a2, t + 2, 0); issueA(a2, t + 2, 1); }
    __builtin_amdgcn_s_barrier();
    __builtin_amdgcn_s_setprio(1);
    acc[0][0] = __builtin_amdgcn_mfma_f32_16x16x32_bf16(av0, bv0, acc[0][0], 0, 0, 0);
    acc[0][1] = __builtin_amdgcn_mfma_f32_16x16x32_bf16(av0, bv1, acc[0][1], 0, 0, 0);
    acc[0][2] = __builtin_amdgcn_mfma_f32_16x16x32_bf16(av0, bv2, acc[0][2], 0, 0, 0);
    acc[0][3] = __builtin_amdgcn_mfma_f32_16x16x32_bf16(av0, bv3, acc[0][3], 0, 0, 0);
    acc[1][0] = __builtin_amdgcn_mfma_f32_16x16x32_bf16(av1, bv0, acc[1][0], 0, 0, 0);
    acc[1][1] = __builtin_amdgcn_mfma_f32_16x16x32_bf16(av1, bv1, acc[1][1], 0, 0, 0);
    acc[1][2] = __builtin_amdgcn_mfma_f32_16x16x32_bf16(av1, bv2, acc[1][2], 0, 0, 0);
    acc[1][3] = __builtin_amdgcn_mfma_f32_16x16x32_bf16(av1, bv3, acc[1][3], 0, 0, 0);
    __builtin_amdgcn_s_setprio(0);
    __builtin_amdgcn_s_barrier();
    // ---------------- phase 2: bottom half of C (acc[2..3][*]) -------------
    bf16x8 av2 = ldfrag(a0, wm + 32);
    bf16x8 av3 = ldfrag(a0, wm + 48);
    if (pf) { issueB(b2s, t + 2, 0); issueB(b2s, t + 2, 1); }
    __builtin_amdgcn_s_barrier();
    __builtin_amdgcn_s_setprio(1);
    acc[2][0] = __builtin_amdgcn_mfma_f32_16x16x32_bf16(av2, bv0, acc[2][0], 0, 0, 0);
    acc[2][1] = __builtin_amdgcn_mfma_f32_16x16x32_bf16(av2, bv1, acc[2][1], 0, 0, 0);
    acc[2][2] = __builtin_amdgcn_mfma_f32_16x16x32_bf16(av2, bv2, acc[2][2], 0, 0, 0);
    acc[2][3] = __builtin_amdgcn_mfma_f32_16x16x32_bf16(av2, bv3, acc[2][3], 0, 0, 0);
    acc[3][0] = __builtin_amdgcn_mfma_f32_16x16x32_bf16(av3, bv0, acc[3][0], 0, 0, 0);
    acc[3][1] = __builtin_amdgcn_mfma_f32_16x16x32_bf16(av3, bv1, acc[3][1], 0, 0, 0);
    acc[3][2] = __builtin_amdgcn_mfma_f32_16x16x32_bf16(av3, bv2, acc[3][2], 0, 0, 0);
    acc[3][3] = __builtin_amdgcn_mfma_f32_16x16x32_bf16(av3, bv3, acc[3][3], 0, 0, 0);
    __builtin_amdgcn_s_setprio(0);
    // Counted drain: tile t+1 (oldest 4 loads) must land for next iter; keep
    // tile t+2's 4 loads in flight. Tail: drain everything.
    if (pf) asm volatile("s_waitcnt vmcnt(4)" ::: "memory");
    else    asm volatile("s_waitcnt vmcnt(0)" ::: "memory");
    __builtin_amdgcn_s_barrier();
    // rotate 3-deep buffers: a0 <- a1 <- a2 <- (freed a0)
    u16* ta_ = a0; a0 = a1; a1 = a2; a2 = ta_;
    u16* tb_ = b0; b0 = b1; b1 = b2s; b2s = tb_;
  }

  // epilogue: C/D layout col=lane&15, row=quad*4+reg
#pragma unroll
  for (int nt = 0; nt < 4; ++nt) {
    int col = j0 + wn + nt * 16 + r16;
    float bias = b2[col];
#pragma unroll
    for (int mt = 0; mt < 4; ++mt) {
      int rbase = i0 + wm + mt * 16 + quad * 4;
#pragma unroll
      for (int r = 0; r < 4; ++r) {
        size_t idx = (size_t)(rbase + r) * DIMD + col;
        out[idx] = ifeats[idx] + bias + acc[mt][nt][r];
      }
    }
  }
}

// ---------------------------------------------------------------------------
extern "C" void kernel_launch(void* const* d_in, const int* in_sizes, int n_in,
                              void* d_out, int out_size, void* d_ws, size_t ws_size,
                              hipStream_t stream) {
  const float* ifeats = (const float*)d_in[0];
  const float* tn     = (const float*)d_in[1];
  const float* ta     = (const float*)d_in[2];
  const float* cw     = (const float*)d_in[3];
  const float* cb     = (const float*)d_in[4];
  const float* w2     = (const float*)d_in[5];
  const float* b2     = (const float*)d_in[6];
  float* out = (float*)d_out;

  // ws: [0, 4MB) w2 bf16 | [4MB, 36MB) x2 bf16
  u16* w2b = (u16*)d_ws;
  u16* x2  = (u16*)((char*)d_ws + (size_t)DIMD * KDIM * 2);

  pre_kernel<<<NROWS + (DIMD * KDIM / 8) / 256, 256, 0, stream>>>(
      ifeats, tn, ta, cw, cb, w2, x2, w2b);
  gemm_bt<<<512, 256, 0, stream>>>(x2, w2b, ifeats, b2, out);
}